// Round 7
// baseline (4201803.516 us; speedup 1.0000x reference)
//
#include <hip/hip_runtime.h>
#include <hip/hip_bf16.h>

typedef __attribute__((ext_vector_type(8))) short bf16x8;
typedef __attribute__((ext_vector_type(4))) float f32x4;

// sizes: T=512 B=64 K=256 H=512 G=4H=2048
// ws layout (bytes):
static constexpr size_t XG_OFF   = 0;                        // bf16 Xg [32768][2048]  134217728 B
static constexpr size_t WXT_OFF  = 134217728;                // bf16 frag-tiled W_x     1048576 B
static constexpr size_t WHT_OFF  = WXT_OFF + 1048576;        // bf16 frag-tiled W_h     2097152 B
static constexpr size_t HBUF_OFF = WHT_OFF + 2097152;        // tagged h dbuf            262144 B
// hbuf: [par(2)][group(4)][slice(16)][512] dwords; dword = (bf16(h)<<16) | step_tag

static __device__ __forceinline__ short f2bf(float f) {
    union { float f; unsigned u; } v; v.f = f;
    return (short)((v.u + 0x7fff + ((v.u >> 16) & 1)) >> 16);   // RNE
}
static __device__ __forceinline__ float bf2f(short s) {
    union { unsigned u; float f; } v;
    v.u = ((unsigned)(unsigned short)s) << 16; return v.f;
}
static __device__ __forceinline__ float sigm(float x)  { return 1.f / (1.f + __expf(-x)); }
static __device__ __forceinline__ float tanh_(float x) { return 1.f - 2.f / (1.f + __expf(2.f * x)); }

// ---------------- prep: convert+transpose W_x/W_h into MFMA B-fragment tiling --------------
__global__ __launch_bounds__(256) void lstm_prep(const float* __restrict__ Wx,
                                                 const float* __restrict__ Wh,
                                                 short* __restrict__ WxT,
                                                 short* __restrict__ WhT) {
    int idx = blockIdx.x * 256 + threadIdx.x;
    if (idx < 524288) {                       // W_x [256][2048]
        int kg = idx >> 11, col = idx & 2047;
        int kt = kg >> 5, k = kg & 31, nt = col >> 4, c = col & 15;
        WxT[(size_t)((kt * 128 + nt) << 9) + c * 32 + k] = f2bf(Wx[idx]);
    } else {                                  // W_h [512][2048] -> 16 slices of 128 cols
        int i2 = idx - 524288;
        int kg = i2 >> 11, col = i2 & 2047;
        int gate = col >> 9, ug = col & 511;
        int sl = ug >> 5, sloc = gate * 32 + (ug & 31);   // slice-local col: gate*32+unit
        int nt = sloc >> 4, c = sloc & 15, kt = kg >> 5, k = kg & 31;
        WhT[((size_t)sl << 16) + ((kt * 8 + nt) << 9) + c * 32 + k] = f2bf(Wh[i2]);
    }
}

// ---------------- phase 1: Xg = bf16(x @ W_x + b), M=32768 N=2048 K=256 --------------------
__global__ __launch_bounds__(256) void lstm_xgemm(const float* __restrict__ x,
                                                  const short* __restrict__ WxT,
                                                  const float* __restrict__ b,
                                                  short* __restrict__ Xg) {
    __shared__ short Alds[128][40];
    int bx = blockIdx.x;
    int xcd = bx & 7, ix = bx >> 3;
    int mp = xcd * 32 + (ix >> 4), np = ix & 15;
    int m0 = mp * 128, n0 = np * 128;
    int tid = threadIdx.x;
    int w = tid >> 6, l = tid & 63;
    int wr = (w >> 1) * 64, wc = (w & 1) * 64;
    int lr = l & 15, lh = l >> 4;
    f32x4 acc[4][4] = {};
    int srow = tid >> 1, sk = (tid & 1) * 16;
    const short* bbase = WxT + lr * 32 + lh * 8;
    int ntg0 = (n0 + wc) >> 4;
    for (int ks = 0; ks < 8; ++ks) {
        int k0 = ks * 32;
        __syncthreads();
        const float* src = x + (size_t)(m0 + srow) * 256 + k0 + sk;
        float4 v0 = *(const float4*)(src + 0);
        float4 v1 = *(const float4*)(src + 4);
        float4 v2 = *(const float4*)(src + 8);
        float4 v3 = *(const float4*)(src + 12);
        bf16x8 p0, p1;
        p0[0]=f2bf(v0.x); p0[1]=f2bf(v0.y); p0[2]=f2bf(v0.z); p0[3]=f2bf(v0.w);
        p0[4]=f2bf(v1.x); p0[5]=f2bf(v1.y); p0[6]=f2bf(v1.z); p0[7]=f2bf(v1.w);
        p1[0]=f2bf(v2.x); p1[1]=f2bf(v2.y); p1[2]=f2bf(v2.z); p1[3]=f2bf(v2.w);
        p1[4]=f2bf(v3.x); p1[5]=f2bf(v3.y); p1[6]=f2bf(v3.z); p1[7]=f2bf(v3.w);
        *(bf16x8*)&Alds[srow][sk]     = p0;
        *(bf16x8*)&Alds[srow][sk + 8] = p1;
        __syncthreads();
        bf16x8 af[4], bfr[4];
        #pragma unroll
        for (int mt = 0; mt < 4; ++mt)
            af[mt] = *(const bf16x8*)&Alds[wr + mt * 16 + lr][lh * 8];
        #pragma unroll
        for (int nt = 0; nt < 4; ++nt)
            bfr[nt] = *(const bf16x8*)(bbase + ((size_t)((ks * 128 + ntg0 + nt)) << 9));
        #pragma unroll
        for (int mt = 0; mt < 4; ++mt)
            #pragma unroll
            for (int nt = 0; nt < 4; ++nt)
                acc[mt][nt] = __builtin_amdgcn_mfma_f32_16x16x32_bf16(af[mt], bfr[nt], acc[mt][nt], 0, 0, 0);
    }
    #pragma unroll
    for (int mt = 0; mt < 4; ++mt) {
        #pragma unroll
        for (int nt = 0; nt < 4; ++nt) {
            int col = n0 + wc + nt * 16 + lr;
            float bb = b[col];
            #pragma unroll
            for (int j = 0; j < 4; ++j) {
                int row = m0 + wr + mt * 16 + lh * 4 + j;
                Xg[(size_t)row * 2048 + col] = f2bf(acc[mt][nt][j] + bb);
            }
        }
    }
}

// ---------------- phase 2: persistent recurrence ------------------------------------------
// 64 WGs = 4 batch-groups (16 rows) x 16 hidden-slices (32 units = 128 gate cols).
// Exchange: tagged dwords (data+step fused) in MALL via relaxed agent atomics.
// One consumer round-trip per step: the poll load IS the data load. No counters, no fences.
// W_h fragments live in VGPRs (64/thread), loaded once.
__global__ __launch_bounds__(512) void lstm_rec(const short* __restrict__ Xg,
                                                const short* __restrict__ WhT,
                                                float* __restrict__ out,
                                                unsigned* __restrict__ hbuf) {
    __shared__ short hlds[16][520];   // h_t for this group's 16 rows (bf16)
    __shared__ float glds[16][132];   // gate block (4 gates x 32 units), padded
    int bx = blockIdx.x;
    int g = bx >> 4, sl = bx & 15;
    int r0 = g * 16, u0 = sl * 32;
    int tid = threadIdx.x;
    int w = tid >> 6, l = tid & 63;
    int lr = l & 15, lh = l >> 4;
    int erow = tid >> 5, eunit = tid & 31;
    // hoist W_h B-fragments into registers: 16 kt-steps x bf16x8 = 64 VGPRs
    bf16x8 wreg[16];
    {
        const short* whb = WhT + ((size_t)sl << 16) + lr * 32 + lh * 8;
        #pragma unroll
        for (int kt = 0; kt < 16; ++kt)
            wreg[kt] = *(const bf16x8*)(whb + ((kt * 8 + w) << 9));
    }
    int crow = l >> 2;          // LDS row this lane deposits (chunk = 16 rows x 32 units)
    int cub  = (l & 3) * 8;     // unit base within chunk

    float creg, h;
    // ---- t = 0: h0 = 0 -> gates = Xg[0] only (no exchange, no MFMA) ----
    {
        size_t xb = (size_t)(r0 + erow) * 2048 + u0 + eunit;
        float gi = sigm(bf2f(Xg[xb +    0]));
        float gg = tanh_(bf2f(Xg[xb + 1024]));
        float go = sigm(bf2f(Xg[xb + 1536]));
        creg = gi * gg;                       // f*c0 = 0
        h = go * tanh_(creg);
        out[(size_t)(r0 + erow) * 512 + u0 + eunit] = h;
        unsigned pay = ((unsigned)(unsigned short)f2bf(h) << 16) | 1u;
        __hip_atomic_store(&hbuf[(size_t)(((4 + g) * 16 + sl) * 512 + tid)], pay,
                           __ATOMIC_RELAXED, __HIP_MEMORY_SCOPE_AGENT);
    }
    // prefetch Xg for t=1
    float xi_c, xf_c, xg_c, xo_c;
    {
        size_t xb = (size_t)131072 + (size_t)(r0 + erow) * 2048 + u0 + eunit;
        xi_c = bf2f(Xg[xb]);        xf_c = bf2f(Xg[xb +  512]);
        xg_c = bf2f(Xg[xb + 1024]); xo_c = bf2f(Xg[xb + 1536]);
    }
    for (int t = 1; t < 512; ++t) {
        // prefetch Xg[t+1] (clamped) — consumed next iteration
        int tn = (t < 511) ? t + 1 : 511;
        size_t xbn = (size_t)tn * 131072 + (size_t)(r0 + erow) * 2048 + u0 + eunit;
        float xi_n = bf2f(Xg[xbn]);        float xf_n = bf2f(Xg[xbn +  512]);
        float xg_n = bf2f(Xg[xbn + 1024]); float xo_n = bf2f(Xg[xbn + 1536]);
        // poll this wave's two chunks; tagged dword == data + validity in one load
        unsigned base = (unsigned)((((t & 1) * 4 + g) * 16) * 512);
        const unsigned* cb0 = hbuf + base + (2 * w)     * 512 + l * 8;
        const unsigned* cb1 = hbuf + base + (2 * w + 1) * 512 + l * 8;
        unsigned v0[8], v1[8];
        unsigned tag = (unsigned)t;
        for (;;) {
            bool ok = true;
            #pragma unroll
            for (int j = 0; j < 8; ++j)
                v0[j] = __hip_atomic_load(cb0 + j, __ATOMIC_RELAXED, __HIP_MEMORY_SCOPE_AGENT);
            #pragma unroll
            for (int j = 0; j < 8; ++j)
                v1[j] = __hip_atomic_load(cb1 + j, __ATOMIC_RELAXED, __HIP_MEMORY_SCOPE_AGENT);
            #pragma unroll
            for (int j = 0; j < 8; ++j)
                ok = ok && ((v0[j] & 0xffffu) == tag) && ((v1[j] & 0xffffu) == tag);
            if (__all(ok)) break;
        }
        bf16x8 p0, p1;
        #pragma unroll
        for (int j = 0; j < 8; ++j) { p0[j] = (short)(v0[j] >> 16); p1[j] = (short)(v1[j] >> 16); }
        *(bf16x8*)&hlds[crow][(2 * w)     * 32 + cub] = p0;
        *(bf16x8*)&hlds[crow][(2 * w + 1) * 32 + cub] = p1;
        __syncthreads();
        // gates_h = h_t @ Wh_slice : two independent MFMA chains
        f32x4 acc0 = {}, acc1 = {};
        #pragma unroll
        for (int kt = 0; kt < 16; kt += 2) {
            bf16x8 a0 = *(const bf16x8*)&hlds[lr][kt * 32 + lh * 8];
            bf16x8 a1 = *(const bf16x8*)&hlds[lr][(kt + 1) * 32 + lh * 8];
            acc0 = __builtin_amdgcn_mfma_f32_16x16x32_bf16(a0, wreg[kt],     acc0, 0, 0, 0);
            acc1 = __builtin_amdgcn_mfma_f32_16x16x32_bf16(a1, wreg[kt + 1], acc1, 0, 0, 0);
        }
        #pragma unroll
        for (int j = 0; j < 4; ++j)
            glds[lh * 4 + j][w * 16 + lr] = acc0[j] + acc1[j];
        __syncthreads();
        // elementwise cell
        float gi = sigm(glds[erow][eunit +  0] + xi_c);
        float gf = sigm(glds[erow][eunit + 32] + xf_c);
        float gg = tanh_(glds[erow][eunit + 64] + xg_c);
        float go = sigm(glds[erow][eunit + 96] + xo_c);
        creg = gf * creg + gi * gg;
        h = go * tanh_(creg);
        out[(size_t)t * 32768 + (size_t)(r0 + erow) * 512 + u0 + eunit] = h;
        if (t == 511) {
            out[(size_t)16777216 +         (size_t)(r0 + erow) * 512 + u0 + eunit] = h;      // hT
            out[(size_t)16777216 + 32768 + (size_t)(r0 + erow) * 512 + u0 + eunit] = creg;   // cT
        } else {
            unsigned pay = ((unsigned)(unsigned short)f2bf(h) << 16) | (unsigned)(t + 1);
            __hip_atomic_store(&hbuf[(size_t)((((((t + 1) & 1) * 4 + g) * 16 + sl) * 512) + tid)],
                               pay, __ATOMIC_RELAXED, __HIP_MEMORY_SCOPE_AGENT);
        }
        xi_c = xi_n; xf_c = xf_n; xg_c = xg_n; xo_c = xo_n;
    }
}

extern "C" void kernel_launch(void* const* d_in, const int* in_sizes, int n_in,
                              void* d_out, int out_size, void* d_ws, size_t ws_size,
                              hipStream_t stream) {
    const float* x  = (const float*)d_in[0];
    const float* Wx = (const float*)d_in[1];
    const float* Wh = (const float*)d_in[2];
    const float* b  = (const float*)d_in[3];
    float* out = (float*)d_out;
    char* ws = (char*)d_ws;
    short* Xg      = (short*)(ws + XG_OFF);
    short* WxT     = (short*)(ws + WXT_OFF);
    short* WhT     = (short*)(ws + WHT_OFF);
    unsigned* hbuf = (unsigned*)(ws + HBUF_OFF);

    lstm_prep <<<6144, 256, 0, stream>>>(Wx, Wh, WxT, WhT);
    lstm_xgemm<<<4096, 256, 0, stream>>>(x, WxT, b, Xg);
    lstm_rec  <<<64,   512, 0, stream>>>(Xg, WhT, out, hbuf);
}

// Round 8
// 2357.452 us; speedup vs baseline: 1782.3493x; 1782.3493x over previous
//
#include <hip/hip_runtime.h>
#include <hip/hip_bf16.h>

typedef __attribute__((ext_vector_type(8))) short bf16x8;
typedef __attribute__((ext_vector_type(4))) float f32x4;

// sizes: T=512 B=64 K=256 H=512 G=4H=2048
// ws layout (bytes):
static constexpr size_t XG_OFF   = 0;                        // bf16 Xg [32768][2048]  134217728 B
static constexpr size_t WXT_OFF  = 134217728;                // bf16 frag-tiled W_x     1048576 B
static constexpr size_t WHT_OFF  = WXT_OFF + 1048576;        // bf16 frag-tiled W_h     2097152 B
static constexpr size_t HBUF_OFF = WHT_OFF + 2097152;        // packed-bf16 h dbuf       131072 B
static constexpr size_t BAR_OFF  = HBUF_OFF + 131072;        // 4 barrier counters          256 B
// hbuf: [par(2)][64 rows][256 pair-dwords]; dword = 2 x bf16. h_t lives in buf[t&1].

static __device__ __forceinline__ short f2bf(float f) {
    union { float f; unsigned u; } v; v.f = f;
    return (short)((v.u + 0x7fff + ((v.u >> 16) & 1)) >> 16);   // RNE
}
static __device__ __forceinline__ float bf2f(short s) {
    union { unsigned u; float f; } v;
    v.u = ((unsigned)(unsigned short)s) << 16; return v.f;
}
static __device__ __forceinline__ float sigm(float x)  { return 1.f / (1.f + __expf(-x)); }
static __device__ __forceinline__ float tanh_(float x) { return 1.f - 2.f / (1.f + __expf(2.f * x)); }

// ---------------- prep: convert+transpose W_x/W_h into MFMA B-fragment tiling, zero barrier ----
__global__ __launch_bounds__(256) void lstm_prep(const float* __restrict__ Wx,
                                                 const float* __restrict__ Wh,
                                                 short* __restrict__ WxT,
                                                 short* __restrict__ WhT,
                                                 int* __restrict__ bar) {
    int idx = blockIdx.x * 256 + threadIdx.x;
    if (idx < 524288) {                       // W_x [256][2048]
        int kg = idx >> 11, col = idx & 2047;
        int kt = kg >> 5, k = kg & 31, nt = col >> 4, c = col & 15;
        WxT[(size_t)((kt * 128 + nt) << 9) + c * 32 + k] = f2bf(Wx[idx]);
    } else if (idx < 524288 + 1048576) {      // W_h [512][2048] -> 16 slices of 128 cols
        int i2 = idx - 524288;
        int kg = i2 >> 11, col = i2 & 2047;
        int gate = col >> 9, ug = col & 511;
        int sl = ug >> 5, sloc = gate * 32 + (ug & 31);   // slice-local col: gate*32+unit
        int nt = sloc >> 4, c = sloc & 15, kt = kg >> 5, k = kg & 31;
        WhT[((size_t)sl << 16) + ((kt * 8 + nt) << 9) + c * 32 + k] = f2bf(Wh[i2]);
    } else if (idx < 524288 + 1048576 + 64) {
        bar[idx - (524288 + 1048576)] = 0;    // poisoned 0xAA... -> must zero before lstm_rec
    }
}

// ---------------- phase 1: Xg = bf16(x @ W_x + b), M=32768 N=2048 K=256 --------------------
__global__ __launch_bounds__(256) void lstm_xgemm(const float* __restrict__ x,
                                                  const short* __restrict__ WxT,
                                                  const float* __restrict__ b,
                                                  short* __restrict__ Xg) {
    __shared__ short Alds[128][40];
    int bx = blockIdx.x;
    int xcd = bx & 7, ix = bx >> 3;
    int mp = xcd * 32 + (ix >> 4), np = ix & 15;
    int m0 = mp * 128, n0 = np * 128;
    int tid = threadIdx.x;
    int w = tid >> 6, l = tid & 63;
    int wr = (w >> 1) * 64, wc = (w & 1) * 64;
    int lr = l & 15, lh = l >> 4;
    f32x4 acc[4][4] = {};
    int srow = tid >> 1, sk = (tid & 1) * 16;
    const short* bbase = WxT + lr * 32 + lh * 8;
    int ntg0 = (n0 + wc) >> 4;
    for (int ks = 0; ks < 8; ++ks) {
        int k0 = ks * 32;
        __syncthreads();
        const float* src = x + (size_t)(m0 + srow) * 256 + k0 + sk;
        float4 v0 = *(const float4*)(src + 0);
        float4 v1 = *(const float4*)(src + 4);
        float4 v2 = *(const float4*)(src + 8);
        float4 v3 = *(const float4*)(src + 12);
        bf16x8 p0, p1;
        p0[0]=f2bf(v0.x); p0[1]=f2bf(v0.y); p0[2]=f2bf(v0.z); p0[3]=f2bf(v0.w);
        p0[4]=f2bf(v1.x); p0[5]=f2bf(v1.y); p0[6]=f2bf(v1.z); p0[7]=f2bf(v1.w);
        p1[0]=f2bf(v2.x); p1[1]=f2bf(v2.y); p1[2]=f2bf(v2.z); p1[3]=f2bf(v2.w);
        p1[4]=f2bf(v3.x); p1[5]=f2bf(v3.y); p1[6]=f2bf(v3.z); p1[7]=f2bf(v3.w);
        *(bf16x8*)&Alds[srow][sk]     = p0;
        *(bf16x8*)&Alds[srow][sk + 8] = p1;
        __syncthreads();
        bf16x8 af[4], bfr[4];
        #pragma unroll
        for (int mt = 0; mt < 4; ++mt)
            af[mt] = *(const bf16x8*)&Alds[wr + mt * 16 + lr][lh * 8];
        #pragma unroll
        for (int nt = 0; nt < 4; ++nt)
            bfr[nt] = *(const bf16x8*)(bbase + ((size_t)((ks * 128 + ntg0 + nt)) << 9));
        #pragma unroll
        for (int mt = 0; mt < 4; ++mt)
            #pragma unroll
            for (int nt = 0; nt < 4; ++nt)
                acc[mt][nt] = __builtin_amdgcn_mfma_f32_16x16x32_bf16(af[mt], bfr[nt], acc[mt][nt], 0, 0, 0);
    }
    #pragma unroll
    for (int mt = 0; mt < 4; ++mt) {
        #pragma unroll
        for (int nt = 0; nt < 4; ++nt) {
            int col = n0 + wc + nt * 16 + lr;
            float bb = b[col];
            #pragma unroll
            for (int j = 0; j < 4; ++j) {
                int row = m0 + wr + mt * 16 + lh * 4 + j;
                Xg[(size_t)row * 2048 + col] = f2bf(acc[mt][nt][j] + bb);
            }
        }
    }
}

// ---------------- phase 2: persistent recurrence ------------------------------------------
// 64 WGs = 4 batch-groups (16 rows) x 16 hidden-slices (32 units = 128 gate cols).
// Sync: R3's proven counter barrier — NARROW polling only (tid0 + s_sleep backoff);
// wide/tight polling causes a MALL congestion storm (R7: 8ms/step).
// W_h fragments in VGPRs (loaded once); Xg prefetched one step ahead; t=0 special-cased.
__global__ __launch_bounds__(512) void lstm_rec(const short* __restrict__ Xg,
                                                const short* __restrict__ WhT,
                                                float* __restrict__ out,
                                                unsigned* __restrict__ hbuf,
                                                int* __restrict__ bar) {
    __shared__ short hlds[16][520];   // h_{t-1} for this group's 16 rows (bf16)
    __shared__ float glds[16][132];   // gate block (4 gates x 32 units), padded
    int bx = blockIdx.x;
    int g = bx >> 4, sl = bx & 15;
    int r0 = g * 16, u0 = sl * 32;
    int tid = threadIdx.x;
    int w = tid >> 6, l = tid & 63;
    int lr = l & 15, lh = l >> 4;
    int erow = tid >> 5, eunit = tid & 31;
    int* barg = bar + g * 16;                       // 64B apart
    // hoist W_h B-fragments into registers: 16 kt-steps x bf16x8 = 64 VGPRs
    bf16x8 wreg[16];
    {
        const short* whb = WhT + ((size_t)sl << 16) + lr * 32 + lh * 8;
        #pragma unroll
        for (int kt = 0; kt < 16; ++kt)
            wreg[kt] = *(const bf16x8*)(whb + ((kt * 8 + w) << 9));
    }

    float creg, h;
    // ---- t = 0: h0 = 0 -> gates = Xg[0] only (no MFMA); publish h_0, barrier, load ----
    {
        size_t xb = (size_t)(r0 + erow) * 2048 + u0 + eunit;
        float gi = sigm(bf2f(Xg[xb +    0]));
        float gg = tanh_(bf2f(Xg[xb + 1024]));
        float go = sigm(bf2f(Xg[xb + 1536]));
        creg = gi * gg;                       // f*c0 = 0
        h = go * tanh_(creg);
        out[(size_t)(r0 + erow) * 512 + u0 + eunit] = h;
        float hn = __shfl_xor(h, 1);
        if ((eunit & 1) == 0) {
            unsigned p = (unsigned)(unsigned short)f2bf(h)
                       | ((unsigned)(unsigned short)f2bf(hn) << 16);
            __hip_atomic_store(&hbuf[(r0 + erow) * 256 + ((u0 + eunit) >> 1)],   // buf[0]
                               p, __ATOMIC_RELAXED, __HIP_MEMORY_SCOPE_AGENT);
        }
        __syncthreads();                      // drains vmcnt -> stores at coherence point
        if (tid == 0) {
            __hip_atomic_fetch_add(barg, 1, __ATOMIC_RELAXED, __HIP_MEMORY_SCOPE_AGENT);
            while (__hip_atomic_load(barg, __ATOMIC_RELAXED, __HIP_MEMORY_SCOPE_AGENT) < 16)
                __builtin_amdgcn_s_sleep(1);
        }
        __syncthreads();
        {   // hlds <- h_0 (buf[0])
            const unsigned* src2 = hbuf + (r0 + erow) * 256 + eunit * 8;
            unsigned pv[8];
            #pragma unroll
            for (int j = 0; j < 8; ++j)
                pv[j] = __hip_atomic_load(&src2[j], __ATOMIC_RELAXED, __HIP_MEMORY_SCOPE_AGENT);
            int cb = eunit * 16;
            #pragma unroll
            for (int j = 0; j < 8; ++j)
                *(unsigned*)&hlds[erow][cb + 2 * j] = pv[j];
        }
        __syncthreads();
    }
    // prefetch Xg for t=1
    float xi_c, xf_c, xg_c, xo_c;
    {
        size_t xb = (size_t)131072 + (size_t)(r0 + erow) * 2048 + u0 + eunit;
        xi_c = bf2f(Xg[xb]);        xf_c = bf2f(Xg[xb +  512]);
        xg_c = bf2f(Xg[xb + 1024]); xo_c = bf2f(Xg[xb + 1536]);
    }
    for (int t = 1; t < 512; ++t) {
        // prefetch Xg[t+1] (clamped) — consumed next iteration; hides HBM latency under MFMA
        int tn = (t < 511) ? t + 1 : 511;
        size_t xbn = (size_t)tn * 131072 + (size_t)(r0 + erow) * 2048 + u0 + eunit;
        float xi_n = bf2f(Xg[xbn]);        float xf_n = bf2f(Xg[xbn +  512]);
        float xg_n = bf2f(Xg[xbn + 1024]); float xo_n = bf2f(Xg[xbn + 1536]);
        // gates_h = h_{t-1} @ Wh_slice : two independent MFMA chains, weights in VGPRs
        f32x4 acc0 = {}, acc1 = {};
        #pragma unroll
        for (int kt = 0; kt < 16; kt += 2) {
            bf16x8 a0 = *(const bf16x8*)&hlds[lr][kt * 32 + lh * 8];
            bf16x8 a1 = *(const bf16x8*)&hlds[lr][(kt + 1) * 32 + lh * 8];
            acc0 = __builtin_amdgcn_mfma_f32_16x16x32_bf16(a0, wreg[kt],     acc0, 0, 0, 0);
            acc1 = __builtin_amdgcn_mfma_f32_16x16x32_bf16(a1, wreg[kt + 1], acc1, 0, 0, 0);
        }
        #pragma unroll
        for (int j = 0; j < 4; ++j)
            glds[lh * 4 + j][w * 16 + lr] = acc0[j] + acc1[j];
        __syncthreads();
        // elementwise cell: thread -> (row=tid>>5, unit=tid&31)
        float gi = sigm(glds[erow][eunit +  0] + xi_c);
        float gf = sigm(glds[erow][eunit + 32] + xf_c);
        float gg = tanh_(glds[erow][eunit + 64] + xg_c);
        float go = sigm(glds[erow][eunit + 96] + xo_c);
        creg = gf * creg + gi * gg;
        h = go * tanh_(creg);
        out[(size_t)t * 32768 + (size_t)(r0 + erow) * 512 + u0 + eunit] = h;
        if (t == 511) {
            out[(size_t)16777216 +         (size_t)(r0 + erow) * 512 + u0 + eunit] = h;      // hT
            out[(size_t)16777216 + 32768 + (size_t)(r0 + erow) * 512 + u0 + eunit] = creg;   // cT
        } else {
            int par = t & 1;                  // h_t lives in buf[t&1]
            float hn = __shfl_xor(h, 1);
            if ((eunit & 1) == 0) {
                unsigned p = (unsigned)(unsigned short)f2bf(h)
                           | ((unsigned)(unsigned short)f2bf(hn) << 16);
                __hip_atomic_store(&hbuf[par * 16384 + (r0 + erow) * 256 + ((u0 + eunit) >> 1)],
                                   p, __ATOMIC_RELAXED, __HIP_MEMORY_SCOPE_AGENT);
            }
            __syncthreads();                  // drains vmcnt(0) -> h stores visible
            if (tid == 0) {
                __hip_atomic_fetch_add(barg, 1, __ATOMIC_RELAXED, __HIP_MEMORY_SCOPE_AGENT);
                int tgt = 16 * (t + 1);
                while (__hip_atomic_load(barg, __ATOMIC_RELAXED, __HIP_MEMORY_SCOPE_AGENT) < tgt)
                    __builtin_amdgcn_s_sleep(1);
            }
            __syncthreads();
            {   // hlds <- h_t (full 16 rows x 512)
                const unsigned* src2 = hbuf + par * 16384 + (r0 + erow) * 256 + eunit * 8;
                unsigned pv[8];
                #pragma unroll
                for (int j = 0; j < 8; ++j)
                    pv[j] = __hip_atomic_load(&src2[j], __ATOMIC_RELAXED, __HIP_MEMORY_SCOPE_AGENT);
                int cb = eunit * 16;
                #pragma unroll
                for (int j = 0; j < 8; ++j)
                    *(unsigned*)&hlds[erow][cb + 2 * j] = pv[j];
            }
            __syncthreads();
        }
        xi_c = xi_n; xf_c = xf_n; xg_c = xg_n; xo_c = xo_n;
    }
}

extern "C" void kernel_launch(void* const* d_in, const int* in_sizes, int n_in,
                              void* d_out, int out_size, void* d_ws, size_t ws_size,
                              hipStream_t stream) {
    const float* x  = (const float*)d_in[0];
    const float* Wx = (const float*)d_in[1];
    const float* Wh = (const float*)d_in[2];
    const float* b  = (const float*)d_in[3];
    float* out = (float*)d_out;
    char* ws = (char*)d_ws;
    short* Xg      = (short*)(ws + XG_OFF);
    short* WxT     = (short*)(ws + WXT_OFF);
    short* WhT     = (short*)(ws + WHT_OFF);
    unsigned* hbuf = (unsigned*)(ws + HBUF_OFF);
    int*   bar     = (int*)(ws + BAR_OFF);

    lstm_prep <<<6145, 256, 0, stream>>>(Wx, Wh, WxT, WhT, bar);
    lstm_xgemm<<<4096, 256, 0, stream>>>(x, WxT, b, Xg);
    lstm_rec  <<<64,   512, 0, stream>>>(Xg, WhT, out, hbuf, bar);
}

// Round 10
// 2080.144 us; speedup vs baseline: 2019.9579x; 1.1333x over previous
//
#include <hip/hip_runtime.h>
#include <hip/hip_bf16.h>

typedef __attribute__((ext_vector_type(8))) short bf16x8;
typedef __attribute__((ext_vector_type(4))) float f32x4;

// sizes: T=512 B=64 K=256 H=512 G=4H=2048
// ws layout (bytes):
static constexpr size_t XG_OFF   = 0;                        // bf16 Xg [32768][2048]  134217728 B
static constexpr size_t WXT_OFF  = 134217728;                // bf16 frag-tiled W_x     1048576 B
static constexpr size_t WHT_OFF  = WXT_OFF + 1048576;        // bf16 frag-tiled W_h     2097152 B
static constexpr size_t HBUF_OFF = WHT_OFF + 2097152;        // packed-bf16 h dbuf       131072 B
static constexpr size_t BAR_OFF  = HBUF_OFF + 131072;        // 64 flag dwords, 64B apart  4096 B
// hbuf: [par(2)][64 rows][256 pair-dwords]; dword = 2 x bf16. h_t lives in buf[t&1].
// flags[(g*16+sl)*16] = t+1  <=> WG (g,sl) has published h_t (and finished reading h_{t-1}).
// Parity safety: WG passes step-t poll only after ALL 8 waves confirm their slices >= t
// (collective watch covers all 16 group slices) + __syncthreads -> no laggard readers.

static __device__ __forceinline__ short f2bf(float f) {
    union { float f; unsigned u; } v; v.f = f;
    return (short)((v.u + 0x7fff + ((v.u >> 16) & 1)) >> 16);   // RNE
}
static __device__ __forceinline__ float bf2f(short s) {
    union { unsigned u; float f; } v;
    v.u = ((unsigned)(unsigned short)s) << 16; return v.f;
}
static __device__ __forceinline__ float sigm(float x)  { return 1.f / (1.f + __expf(-x)); }
static __device__ __forceinline__ float tanh_(float x) { return 1.f - 2.f / (1.f + __expf(2.f * x)); }

// ---------------- prep: convert+transpose W_x/W_h into MFMA B-fragment tiling, zero flags ----
__global__ __launch_bounds__(256) void lstm_prep(const float* __restrict__ Wx,
                                                 const float* __restrict__ Wh,
                                                 short* __restrict__ WxT,
                                                 short* __restrict__ WhT,
                                                 int* __restrict__ flags) {
    int idx = blockIdx.x * 256 + threadIdx.x;
    if (idx < 524288) {                       // W_x [256][2048]
        int kg = idx >> 11, col = idx & 2047;
        int kt = kg >> 5, k = kg & 31, nt = col >> 4, c = col & 15;
        WxT[(size_t)((kt * 128 + nt) << 9) + c * 32 + k] = f2bf(Wx[idx]);
    } else if (idx < 524288 + 1048576) {      // W_h [512][2048] -> 16 slices of 128 cols
        int i2 = idx - 524288;
        int kg = i2 >> 11, col = i2 & 2047;
        int gate = col >> 9, ug = col & 511;
        int sl = ug >> 5, sloc = gate * 32 + (ug & 31);   // slice-local col: gate*32+unit
        int nt = sloc >> 4, c = sloc & 15, kt = kg >> 5, k = kg & 31;
        WhT[((size_t)sl << 16) + ((kt * 8 + nt) << 9) + c * 32 + k] = f2bf(Wh[i2]);
    } else if (idx < 524288 + 1048576 + 64) {
        flags[(idx - (524288 + 1048576)) * 16] = 0;   // poisoned 0xAA... -> zero before lstm_rec
    }
}

// ---------------- phase 1: Xg = bf16(x @ W_x + b), M=32768 N=2048 K=256 --------------------
__global__ __launch_bounds__(256) void lstm_xgemm(const float* __restrict__ x,
                                                  const short* __restrict__ WxT,
                                                  const float* __restrict__ b,
                                                  short* __restrict__ Xg) {
    __shared__ short Alds[128][40];
    int bx = blockIdx.x;
    int xcd = bx & 7, ix = bx >> 3;
    int mp = xcd * 32 + (ix >> 4), np = ix & 15;
    int m0 = mp * 128, n0 = np * 128;
    int tid = threadIdx.x;
    int w = tid >> 6, l = tid & 63;
    int wr = (w >> 1) * 64, wc = (w & 1) * 64;
    int lr = l & 15, lh = l >> 4;
    f32x4 acc[4][4] = {};
    int srow = tid >> 1, sk = (tid & 1) * 16;
    const short* bbase = WxT + lr * 32 + lh * 8;
    int ntg0 = (n0 + wc) >> 4;
    for (int ks = 0; ks < 8; ++ks) {
        int k0 = ks * 32;
        __syncthreads();
        const float* src = x + (size_t)(m0 + srow) * 256 + k0 + sk;
        float4 v0 = *(const float4*)(src + 0);
        float4 v1 = *(const float4*)(src + 4);
        float4 v2 = *(const float4*)(src + 8);
        float4 v3 = *(const float4*)(src + 12);
        bf16x8 p0, p1;
        p0[0]=f2bf(v0.x); p0[1]=f2bf(v0.y); p0[2]=f2bf(v0.z); p0[3]=f2bf(v0.w);
        p0[4]=f2bf(v1.x); p0[5]=f2bf(v1.y); p0[6]=f2bf(v1.z); p0[7]=f2bf(v1.w);
        p1[0]=f2bf(v2.x); p1[1]=f2bf(v2.y); p1[2]=f2bf(v2.z); p1[3]=f2bf(v2.w);
        p1[4]=f2bf(v3.x); p1[5]=f2bf(v3.y); p1[6]=f2bf(v3.z); p1[7]=f2bf(v3.w);
        *(bf16x8*)&Alds[srow][sk]     = p0;
        *(bf16x8*)&Alds[srow][sk + 8] = p1;
        __syncthreads();
        bf16x8 af[4], bfr[4];
        #pragma unroll
        for (int mt = 0; mt < 4; ++mt)
            af[mt] = *(const bf16x8*)&Alds[wr + mt * 16 + lr][lh * 8];
        #pragma unroll
        for (int nt = 0; nt < 4; ++nt)
            bfr[nt] = *(const bf16x8*)(bbase + ((size_t)((ks * 128 + ntg0 + nt)) << 9));
        #pragma unroll
        for (int mt = 0; mt < 4; ++mt)
            #pragma unroll
            for (int nt = 0; nt < 4; ++nt)
                acc[mt][nt] = __builtin_amdgcn_mfma_f32_16x16x32_bf16(af[mt], bfr[nt], acc[mt][nt], 0, 0, 0);
    }
    #pragma unroll
    for (int mt = 0; mt < 4; ++mt) {
        #pragma unroll
        for (int nt = 0; nt < 4; ++nt) {
            int col = n0 + wc + nt * 16 + lr;
            float bb = b[col];
            #pragma unroll
            for (int j = 0; j < 4; ++j) {
                int row = m0 + wr + mt * 16 + lh * 4 + j;
                Xg[(size_t)row * 2048 + col] = f2bf(acc[mt][nt][j] + bb);
            }
        }
    }
}

// ---------------- phase 2: persistent recurrence ------------------------------------------
// 64 WGs = 4 batch-groups (16 rows) x 16 hidden-slices (32 units = 128 gate cols).
// Sync: per-slice FLAG broadcast (no counter RMW chain). Producer: publish h -> sync(drain)
// -> tid0 stores flag=t+1. Consumer: wave w narrowly polls its 2 producers' flags (2 dwords,
// s_sleep backoff), then immediately reloads its 2 slices of h. Wide polling forbidden (R7).
__global__ __launch_bounds__(512) void lstm_rec(const short* __restrict__ Xg,
                                                const short* __restrict__ WhT,
                                                float* __restrict__ out,
                                                unsigned* __restrict__ hbuf,
                                                int* __restrict__ flags) {
    __shared__ short hlds[16][520];   // h_{t-1} for this group's 16 rows (bf16)
    __shared__ float glds[16][132];   // gate block (4 gates x 32 units), padded
    int bx = blockIdx.x;
    int g = bx >> 4, sl = bx & 15;
    int r0 = g * 16, u0 = sl * 32;
    int tid = threadIdx.x;
    int w = tid >> 6, l = tid & 63;
    int lr = l & 15, lh = l >> 4;
    int erow = tid >> 5, eunit = tid & 31;
    // hoist W_h B-fragments into registers: 16 kt-steps x bf16x8 = 64 VGPRs
    bf16x8 wreg[16];
    {
        const short* whb = WhT + ((size_t)sl << 16) + lr * 32 + lh * 8;
        #pragma unroll
        for (int kt = 0; kt < 16; ++kt)
            wreg[kt] = *(const bf16x8*)(whb + ((kt * 8 + w) << 9));
    }
    // per-wave reload geometry: wave w owns slices 2w, 2w+1 (units 64w .. 64w+63)
    int drow = l >> 2;                 // 0..15
    int dq   = l & 3;                  // 0..3
    int dub  = 64 * w + dq * 16;       // unit base in hlds row
    int dpd  = 32 * w + dq * 8;        // pair-dword base in hbuf row
    int fidx = (g * 16 + 2 * w + (l & 1)) * 16;   // this lane's producer flag (2 per wave)
    int myflag = (g * 16 + sl) * 16;

    float creg, h;
    // ---- t = 0: h0 = 0 -> gates = Xg[0] only (no MFMA); publish h_0; flag=1 ----
    {
        size_t xb = (size_t)(r0 + erow) * 2048 + u0 + eunit;
        float gi = sigm(bf2f(Xg[xb +    0]));
        float gg = tanh_(bf2f(Xg[xb + 1024]));
        float go = sigm(bf2f(Xg[xb + 1536]));
        creg = gi * gg;                       // f*c0 = 0
        h = go * tanh_(creg);
        out[(size_t)(r0 + erow) * 512 + u0 + eunit] = h;
        float hn = __shfl_xor(h, 1);
        if ((eunit & 1) == 0) {
            unsigned p = (unsigned)(unsigned short)f2bf(h)
                       | ((unsigned)(unsigned short)f2bf(hn) << 16);
            __hip_atomic_store(&hbuf[(r0 + erow) * 256 + ((u0 + eunit) >> 1)],   // buf[0]
                               p, __ATOMIC_RELAXED, __HIP_MEMORY_SCOPE_AGENT);
        }
        __syncthreads();                      // drains vmcnt -> h_0 at coherence point
        if (tid == 0)
            __hip_atomic_store(&flags[myflag], 1, __ATOMIC_RELAXED, __HIP_MEMORY_SCOPE_AGENT);
    }
    // prefetch Xg for t=1
    float xi_c, xf_c, xg_c, xo_c;
    {
        size_t xb = (size_t)131072 + (size_t)(r0 + erow) * 2048 + u0 + eunit;
        xi_c = bf2f(Xg[xb]);        xf_c = bf2f(Xg[xb +  512]);
        xg_c = bf2f(Xg[xb + 1024]); xo_c = bf2f(Xg[xb + 1536]);
    }
    for (int t = 1; t < 512; ++t) {
        // prefetch Xg[t+1] (clamped) — in flight during poll+reload+MFMA
        int tn = (t < 511) ? t + 1 : 511;
        size_t xbn = (size_t)tn * 131072 + (size_t)(r0 + erow) * 2048 + u0 + eunit;
        float xi_n = bf2f(Xg[xbn]);        float xf_n = bf2f(Xg[xbn +  512]);
        float xg_n = bf2f(Xg[xbn + 1024]); float xo_n = bf2f(Xg[xbn + 1536]);
        // ---- per-wave narrow poll: wait until both producer slices published h_{t-1} ----
        for (;;) {
            int f = __hip_atomic_load(&flags[fidx], __ATOMIC_RELAXED, __HIP_MEMORY_SCOPE_AGENT);
            if (__all(f >= t)) break;
            __builtin_amdgcn_s_sleep(1);
        }
        asm volatile("" ::: "memory");        // no compiler reordering of data loads above poll
        // ---- reload this wave's 2 slices of h_{t-1} and deposit to LDS ----
        {
            const unsigned* src2 = hbuf + ((t - 1) & 1) * 16384 + (r0 + drow) * 256 + dpd;
            unsigned pv[8];
            #pragma unroll
            for (int j = 0; j < 8; ++j)
                pv[j] = __hip_atomic_load(&src2[j], __ATOMIC_RELAXED, __HIP_MEMORY_SCOPE_AGENT);
            #pragma unroll
            for (int j = 0; j < 8; ++j)
                *(unsigned*)&hlds[drow][dub + 2 * j] = pv[j];
        }
        __syncthreads();
        // gates_h = h_{t-1} @ Wh_slice : two independent MFMA chains, weights in VGPRs
        f32x4 acc0 = {}, acc1 = {};
        #pragma unroll
        for (int kt = 0; kt < 16; kt += 2) {
            bf16x8 a0 = *(const bf16x8*)&hlds[lr][kt * 32 + lh * 8];
            bf16x8 a1 = *(const bf16x8*)&hlds[lr][(kt + 1) * 32 + lh * 8];
            acc0 = __builtin_amdgcn_mfma_f32_16x16x32_bf16(a0, wreg[kt],     acc0, 0, 0, 0);
            acc1 = __builtin_amdgcn_mfma_f32_16x16x32_bf16(a1, wreg[kt + 1], acc1, 0, 0, 0);
        }
        #pragma unroll
        for (int j = 0; j < 4; ++j)
            glds[lh * 4 + j][w * 16 + lr] = acc0[j] + acc1[j];
        __syncthreads();
        // elementwise cell: thread -> (row=tid>>5, unit=tid&31)
        float gi = sigm(glds[erow][eunit +  0] + xi_c);
        float gf = sigm(glds[erow][eunit + 32] + xf_c);
        float gg = tanh_(glds[erow][eunit + 64] + xg_c);
        float go = sigm(glds[erow][eunit + 96] + xo_c);
        creg = gf * creg + gi * gg;
        h = go * tanh_(creg);
        out[(size_t)t * 32768 + (size_t)(r0 + erow) * 512 + u0 + eunit] = h;
        if (t == 511) {
            out[(size_t)16777216 +         (size_t)(r0 + erow) * 512 + u0 + eunit] = h;      // hT
            out[(size_t)16777216 + 32768 + (size_t)(r0 + erow) * 512 + u0 + eunit] = creg;   // cT
        } else {
            float hn = __shfl_xor(h, 1);
            if ((eunit & 1) == 0) {
                unsigned p = (unsigned)(unsigned short)f2bf(h)
                           | ((unsigned)(unsigned short)f2bf(hn) << 16);
                __hip_atomic_store(&hbuf[(t & 1) * 16384 + (r0 + erow) * 256 + ((u0 + eunit) >> 1)],
                                   p, __ATOMIC_RELAXED, __HIP_MEMORY_SCOPE_AGENT);
            }
            __syncthreads();                  // drains vmcnt(0) -> h_t at coherence point
            if (tid == 0)
                __hip_atomic_store(&flags[myflag], t + 1, __ATOMIC_RELAXED, __HIP_MEMORY_SCOPE_AGENT);
        }
        xi_c = xi_n; xf_c = xf_n; xg_c = xg_n; xo_c = xo_n;
    }
}

extern "C" void kernel_launch(void* const* d_in, const int* in_sizes, int n_in,
                              void* d_out, int out_size, void* d_ws, size_t ws_size,
                              hipStream_t stream) {
    const float* x  = (const float*)d_in[0];
    const float* Wx = (const float*)d_in[1];
    const float* Wh = (const float*)d_in[2];
    const float* b  = (const float*)d_in[3];
    float* out = (float*)d_out;
    char* ws = (char*)d_ws;
    short* Xg      = (short*)(ws + XG_OFF);
    short* WxT     = (short*)(ws + WXT_OFF);
    short* WhT     = (short*)(ws + WHT_OFF);
    unsigned* hbuf = (unsigned*)(ws + HBUF_OFF);
    int*   flags   = (int*)(ws + BAR_OFF);

    lstm_prep <<<6145, 256, 0, stream>>>(Wx, Wh, WxT, WhT, flags);
    lstm_xgemm<<<4096, 256, 0, stream>>>(x, WxT, b, Xg);
    lstm_rec  <<<64,   512, 0, stream>>>(Xg, WhT, out, hbuf, flags);
}

// Round 12
// 1327.110 us; speedup vs baseline: 3166.1314x; 1.5674x over previous
//
#include <hip/hip_runtime.h>
#include <hip/hip_bf16.h>

typedef __attribute__((ext_vector_type(8))) short bf16x8;
typedef __attribute__((ext_vector_type(4))) float f32x4;

// sizes: T=512 B=64 K=256 H=512 G=4H=2048
// ws layout (bytes):
static constexpr size_t XG_OFF   = 0;                        // bf16 Xg [32768][2048]  134217728 B
static constexpr size_t WXT_OFF  = 134217728;                // bf16 frag-tiled W_x     1048576 B
static constexpr size_t WHT_OFF  = WXT_OFF + 1048576;        // bf16 frag-tiled W_h     2097152 B
static constexpr size_t HBUF_OFF = WHT_OFF + 2097152;        // packed-bf16 h dbuf       131072 B
static constexpr size_t BAR_OFF  = HBUF_OFF + 131072;        // 64 flag dwords, 64B apart  4096 B
// hbuf: [par(2)][64 rows][256 pair-dwords]; dword = 2 x bf16. h_t lives in buf[t&1].
// flags[(g*16+sl)*16] = t+1  <=> WG (g,sl) published h_t (and finished reading h_{t-1}).
// Parity safety: WG passes step-t poll only after ALL 8 waves confirm (collective watch
// spans all 16 group slices) + __syncthreads -> no laggard readers when buf reused.

static __device__ __forceinline__ short f2bf(float f) {
    union { float f; unsigned u; } v; v.f = f;
    return (short)((v.u + 0x7fff + ((v.u >> 16) & 1)) >> 16);   // RNE
}
static __device__ __forceinline__ float bf2f(short s) {
    union { unsigned u; float f; } v;
    v.u = ((unsigned)(unsigned short)s) << 16; return v.f;
}
static __device__ __forceinline__ float sigm(float x)  { return 1.f / (1.f + __expf(-x)); }
static __device__ __forceinline__ float tanh_(float x) { return 1.f - 2.f / (1.f + __expf(2.f * x)); }

// ---------------- prep: convert+transpose W_x/W_h into MFMA B-fragment tiling, zero flags ----
__global__ __launch_bounds__(256) void lstm_prep(const float* __restrict__ Wx,
                                                 const float* __restrict__ Wh,
                                                 short* __restrict__ WxT,
                                                 short* __restrict__ WhT,
                                                 int* __restrict__ flags) {
    int idx = blockIdx.x * 256 + threadIdx.x;
    if (idx < 524288) {                       // W_x [256][2048]
        int kg = idx >> 11, col = idx & 2047;
        int kt = kg >> 5, k = kg & 31, nt = col >> 4, c = col & 15;
        WxT[(size_t)((kt * 128 + nt) << 9) + c * 32 + k] = f2bf(Wx[idx]);
    } else if (idx < 524288 + 1048576) {      // W_h [512][2048] -> 16 slices of 128 cols
        int i2 = idx - 524288;
        int kg = i2 >> 11, col = i2 & 2047;
        int gate = col >> 9, ug = col & 511;
        int sl = ug >> 5, sloc = gate * 32 + (ug & 31);   // slice-local col: gate*32+unit
        int nt = sloc >> 4, c = sloc & 15, kt = kg >> 5, k = kg & 31;
        WhT[((size_t)sl << 16) + ((kt * 8 + nt) << 9) + c * 32 + k] = f2bf(Wh[i2]);
    } else if (idx < 524288 + 1048576 + 64) {
        flags[(idx - (524288 + 1048576)) * 16] = 0;   // poisoned 0xAA... -> zero before lstm_rec
    }
}

// ---------------- phase 1: Xg = bf16(x @ W_x + b), M=32768 N=2048 K=256 --------------------
__global__ __launch_bounds__(256) void lstm_xgemm(const float* __restrict__ x,
                                                  const short* __restrict__ WxT,
                                                  const float* __restrict__ b,
                                                  short* __restrict__ Xg) {
    __shared__ short Alds[128][40];
    int bx = blockIdx.x;
    int xcd = bx & 7, ix = bx >> 3;
    int mp = xcd * 32 + (ix >> 4), np = ix & 15;
    int m0 = mp * 128, n0 = np * 128;
    int tid = threadIdx.x;
    int w = tid >> 6, l = tid & 63;
    int wr = (w >> 1) * 64, wc = (w & 1) * 64;
    int lr = l & 15, lh = l >> 4;
    f32x4 acc[4][4] = {};
    int srow = tid >> 1, sk = (tid & 1) * 16;
    const short* bbase = WxT + lr * 32 + lh * 8;
    int ntg0 = (n0 + wc) >> 4;
    for (int ks = 0; ks < 8; ++ks) {
        int k0 = ks * 32;
        __syncthreads();
        const float* src = x + (size_t)(m0 + srow) * 256 + k0 + sk;
        float4 v0 = *(const float4*)(src + 0);
        float4 v1 = *(const float4*)(src + 4);
        float4 v2 = *(const float4*)(src + 8);
        float4 v3 = *(const float4*)(src + 12);
        bf16x8 p0, p1;
        p0[0]=f2bf(v0.x); p0[1]=f2bf(v0.y); p0[2]=f2bf(v0.z); p0[3]=f2bf(v0.w);
        p0[4]=f2bf(v1.x); p0[5]=f2bf(v1.y); p0[6]=f2bf(v1.z); p0[7]=f2bf(v1.w);
        p1[0]=f2bf(v2.x); p1[1]=f2bf(v2.y); p1[2]=f2bf(v2.z); p1[3]=f2bf(v2.w);
        p1[4]=f2bf(v3.x); p1[5]=f2bf(v3.y); p1[6]=f2bf(v3.z); p1[7]=f2bf(v3.w);
        *(bf16x8*)&Alds[srow][sk]     = p0;
        *(bf16x8*)&Alds[srow][sk + 8] = p1;
        __syncthreads();
        bf16x8 af[4], bfr[4];
        #pragma unroll
        for (int mt = 0; mt < 4; ++mt)
            af[mt] = *(const bf16x8*)&Alds[wr + mt * 16 + lr][lh * 8];
        #pragma unroll
        for (int nt = 0; nt < 4; ++nt)
            bfr[nt] = *(const bf16x8*)(bbase + ((size_t)((ks * 128 + ntg0 + nt)) << 9));
        #pragma unroll
        for (int mt = 0; mt < 4; ++mt)
            #pragma unroll
            for (int nt = 0; nt < 4; ++nt)
                acc[mt][nt] = __builtin_amdgcn_mfma_f32_16x16x32_bf16(af[mt], bfr[nt], acc[mt][nt], 0, 0, 0);
    }
    #pragma unroll
    for (int mt = 0; mt < 4; ++mt) {
        #pragma unroll
        for (int nt = 0; nt < 4; ++nt) {
            int col = n0 + wc + nt * 16 + lr;
            float bb = b[col];
            #pragma unroll
            for (int j = 0; j < 4; ++j) {
                int row = m0 + wr + mt * 16 + lh * 4 + j;
                Xg[(size_t)row * 2048 + col] = f2bf(acc[mt][nt][j] + bb);
            }
        }
    }
}

// ---------------- phase 2: persistent recurrence ------------------------------------------
// 64 WGs = 4 batch-groups (16 rows) x 16 hidden-slices (32 units = 128 gate cols).
// Sync: per-slice FLAG broadcast; producer: h store -> sync(drain, MALL-only now) ->
// tid0 flag=t+1 -> out[] store (off critical path). Consumer: per-wave narrow flag poll
// (2 dwords, s_sleep backoff) then COALESCED reload (consecutive lanes -> consecutive
// dwords, 128B segments). Wide/tight polling & strided reloads forbidden (R7/R10 lessons).
__global__ __launch_bounds__(512) void lstm_rec(const short* __restrict__ Xg,
                                                const short* __restrict__ WhT,
                                                float* __restrict__ out,
                                                unsigned* __restrict__ hbuf,
                                                int* __restrict__ flags) {
    __shared__ short hlds[16][520];   // h_{t-1} for this group's 16 rows (bf16)
    __shared__ float glds[16][132];   // gate block (4 gates x 32 units), padded
    int bx = blockIdx.x;
    int g = bx >> 4, sl = bx & 15;
    int r0 = g * 16, u0 = sl * 32;
    int tid = threadIdx.x;
    int w = tid >> 6, l = tid & 63;
    int lr = l & 15, lh = l >> 4;
    int erow = tid >> 5, eunit = tid & 31;
    // hoist W_h B-fragments into registers: 16 kt-steps x bf16x8 = 64 VGPRs
    bf16x8 wreg[16];
    {
        const short* whb = WhT + ((size_t)sl << 16) + lr * 32 + lh * 8;
        #pragma unroll
        for (int kt = 0; kt < 16; ++kt)
            wreg[kt] = *(const bf16x8*)(whb + ((kt * 8 + w) << 9));
    }
    // coalesced reload geometry: wave w owns pair-dword cols [32w,32w+32) (slices 2w,2w+1);
    // lane l, k=0..7 loads dword (r0 + 2k + (l>>5))*256 + 32w + (l&31) -> 128B runs/32 lanes
    int rrow = l >> 5;                 // 0..1
    int rcol = 32 * w + (l & 31);      // pair-dword col in hbuf row
    int dub  = 64 * w + 2 * (l & 31);  // unit base in hlds row
    int fidx = (g * 16 + 2 * w + (l & 1)) * 16;   // this lane's watched producer flag
    int myflag = (g * 16 + sl) * 16;

    float creg, h;
    // ---- t = 0: h0 = 0 -> gates = Xg[0] only (no MFMA); publish h_0; flag=1; out after ----
    {
        size_t xb = (size_t)(r0 + erow) * 2048 + u0 + eunit;
        float gi = sigm(bf2f(Xg[xb +    0]));
        float gg = tanh_(bf2f(Xg[xb + 1024]));
        float go = sigm(bf2f(Xg[xb + 1536]));
        creg = gi * gg;                       // f*c0 = 0
        h = go * tanh_(creg);
        float hn = __shfl_xor(h, 1);
        if ((eunit & 1) == 0) {
            unsigned p = (unsigned)(unsigned short)f2bf(h)
                       | ((unsigned)(unsigned short)f2bf(hn) << 16);
            __hip_atomic_store(&hbuf[(r0 + erow) * 256 + ((u0 + eunit) >> 1)],   // buf[0]
                               p, __ATOMIC_RELAXED, __HIP_MEMORY_SCOPE_AGENT);
        }
        __syncthreads();                      // drains vmcnt -> h_0 at coherence point
        if (tid == 0)
            __hip_atomic_store(&flags[myflag], 1, __ATOMIC_RELAXED, __HIP_MEMORY_SCOPE_AGENT);
        out[(size_t)(r0 + erow) * 512 + u0 + eunit] = h;   // off critical path
    }
    // prefetch Xg for t=1
    float xi_c, xf_c, xg_c, xo_c;
    {
        size_t xb = (size_t)131072 + (size_t)(r0 + erow) * 2048 + u0 + eunit;
        xi_c = bf2f(Xg[xb]);        xf_c = bf2f(Xg[xb +  512]);
        xg_c = bf2f(Xg[xb + 1024]); xo_c = bf2f(Xg[xb + 1536]);
    }
    for (int t = 1; t < 512; ++t) {
        // prefetch Xg[t+1] (clamped) — in flight during poll+reload+MFMA
        int tn = (t < 511) ? t + 1 : 511;
        size_t xbn = (size_t)tn * 131072 + (size_t)(r0 + erow) * 2048 + u0 + eunit;
        float xi_n = bf2f(Xg[xbn]);        float xf_n = bf2f(Xg[xbn +  512]);
        float xg_n = bf2f(Xg[xbn + 1024]); float xo_n = bf2f(Xg[xbn + 1536]);
        // ---- per-wave narrow poll: both watched producer slices published h_{t-1} ----
        for (;;) {
            int f = __hip_atomic_load(&flags[fidx], __ATOMIC_RELAXED, __HIP_MEMORY_SCOPE_AGENT);
            if (__all(f >= t)) break;
            __builtin_amdgcn_s_sleep(1);
        }
        asm volatile("" ::: "memory");        // no compiler reordering of data loads above poll
        // ---- coalesced reload of this wave's 2 slices of h_{t-1}, deposit to LDS ----
        {
            const unsigned* src2 = hbuf + ((t - 1) & 1) * 16384
                                 + (size_t)(r0 + rrow) * 256 + rcol;
            unsigned pv[8];
            #pragma unroll
            for (int k = 0; k < 8; ++k)
                pv[k] = __hip_atomic_load(src2 + k * 512, __ATOMIC_RELAXED, __HIP_MEMORY_SCOPE_AGENT);
            #pragma unroll
            for (int k = 0; k < 8; ++k)
                *(unsigned*)&hlds[2 * k + rrow][dub] = pv[k];
        }
        __syncthreads();
        // gates_h = h_{t-1} @ Wh_slice : two independent MFMA chains, weights in VGPRs
        f32x4 acc0 = {}, acc1 = {};
        #pragma unroll
        for (int kt = 0; kt < 16; kt += 2) {
            bf16x8 a0 = *(const bf16x8*)&hlds[lr][kt * 32 + lh * 8];
            bf16x8 a1 = *(const bf16x8*)&hlds[lr][(kt + 1) * 32 + lh * 8];
            acc0 = __builtin_amdgcn_mfma_f32_16x16x32_bf16(a0, wreg[kt],     acc0, 0, 0, 0);
            acc1 = __builtin_amdgcn_mfma_f32_16x16x32_bf16(a1, wreg[kt + 1], acc1, 0, 0, 0);
        }
        #pragma unroll
        for (int j = 0; j < 4; ++j)
            glds[lh * 4 + j][w * 16 + lr] = acc0[j] + acc1[j];
        __syncthreads();
        // elementwise cell: thread -> (row=tid>>5, unit=tid&31)
        float gi = sigm(glds[erow][eunit +  0] + xi_c);
        float gf = sigm(glds[erow][eunit + 32] + xf_c);
        float gg = tanh_(glds[erow][eunit + 64] + xg_c);
        float go = sigm(glds[erow][eunit + 96] + xo_c);
        creg = gf * creg + gi * gg;
        h = go * tanh_(creg);
        if (t == 511) {
            out[(size_t)t * 32768 + (size_t)(r0 + erow) * 512 + u0 + eunit] = h;
            out[(size_t)16777216 +         (size_t)(r0 + erow) * 512 + u0 + eunit] = h;      // hT
            out[(size_t)16777216 + 32768 + (size_t)(r0 + erow) * 512 + u0 + eunit] = creg;   // cT
        } else {
            // publish h_t FIRST (MALL), drain, flag, then the HBM out store off-path
            float hn = __shfl_xor(h, 1);
            if ((eunit & 1) == 0) {
                unsigned p = (unsigned)(unsigned short)f2bf(h)
                           | ((unsigned)(unsigned short)f2bf(hn) << 16);
                __hip_atomic_store(&hbuf[(t & 1) * 16384 + (r0 + erow) * 256 + ((u0 + eunit) >> 1)],
                                   p, __ATOMIC_RELAXED, __HIP_MEMORY_SCOPE_AGENT);
            }
            __syncthreads();                  // drains vmcnt(0) -> h_t at coherence point
            if (tid == 0)
                __hip_atomic_store(&flags[myflag], t + 1, __ATOMIC_RELAXED, __HIP_MEMORY_SCOPE_AGENT);
            out[(size_t)t * 32768 + (size_t)(r0 + erow) * 512 + u0 + eunit] = h;
        }
        xi_c = xi_n; xf_c = xf_n; xg_c = xg_n; xo_c = xo_n;
    }
}

extern "C" void kernel_launch(void* const* d_in, const int* in_sizes, int n_in,
                              void* d_out, int out_size, void* d_ws, size_t ws_size,
                              hipStream_t stream) {
    const float* x  = (const float*)d_in[0];
    const float* Wx = (const float*)d_in[1];
    const float* Wh = (const float*)d_in[2];
    const float* b  = (const float*)d_in[3];
    float* out = (float*)d_out;
    char* ws = (char*)d_ws;
    short* Xg      = (short*)(ws + XG_OFF);
    short* WxT     = (short*)(ws + WXT_OFF);
    short* WhT     = (short*)(ws + WHT_OFF);
    unsigned* hbuf = (unsigned*)(ws + HBUF_OFF);
    int*   flags   = (int*)(ws + BAR_OFF);

    lstm_prep <<<6145, 256, 0, stream>>>(Wx, Wh, WxT, WhT, flags);
    lstm_xgemm<<<4096, 256, 0, stream>>>(x, WxT, b, Xg);
    lstm_rec  <<<64,   512, 0, stream>>>(Xg, WhT, out, hbuf, flags);
}